// Round 1
// baseline (767.072 us; speedup 1.0000x reference)
//
#include <hip/hip_runtime.h>
#include <hip/hip_bf16.h>
#include <stdint.h>

#define MULT     4
#define HIDDEN   4096
#define DFULL    (MULT * HIDDEN)   // 16384
#define NTHREADS 256

// bf16 round-to-nearest-even; returns rounded f32 value, outputs the bf16 bits.
__device__ __forceinline__ float bf16_rne(float f, uint32_t* bits) {
    uint32_t u = __float_as_uint(f);
    uint32_t lsb = (u >> 16) & 1u;
    uint32_t r = (u + 0x7fffu + lsb) >> 16;
    *bits = r;
    return __uint_as_float(r << 16);
}

__device__ __forceinline__ float b2f(uint32_t bits) {
    return __uint_as_float(bits << 16);
}

__global__ __launch_bounds__(NTHREADS) void hchead_kernel(
    const float* __restrict__ x, const float* __restrict__ fn,
    const float* __restrict__ scale, const float* __restrict__ base,
    float* __restrict__ out)
{
    __shared__ ushort xb[DFULL];     // 32 KB: bf16 bits of this token's row
    __shared__ float  red[4][5];     // per-wave partials: ss, d0..d3
    __shared__ float  wbc[4];        // broadcast mixing weights

    const int t   = blockIdx.x;
    const int tid = threadIdx.x;
    const float* xr = x + (size_t)t * DFULL;

    float ss = 0.f, d0 = 0.f, d1 = 0.f, d2 = 0.f, d3 = 0.f;

    // Phase 1: single pass over the row. 16 iterations x 1024 elements.
    #pragma unroll
    for (int it = 0; it < DFULL / (NTHREADS * 4); ++it) {
        const int j = it * (NTHREADS * 4) + tid * 4;
        const float4 xv = *reinterpret_cast<const float4*>(xr + j);

        uint32_t bx, by, bz, bw;
        const float f0 = bf16_rne(xv.x, &bx);
        const float f1 = bf16_rne(xv.y, &by);
        const float f2 = bf16_rne(xv.z, &bz);
        const float f3 = bf16_rne(xv.w, &bw);

        ushort4 st;
        st.x = (ushort)bx; st.y = (ushort)by; st.z = (ushort)bz; st.w = (ushort)bw;
        *reinterpret_cast<ushort4*>(&xb[j]) = st;

        ss = fmaf(f0, f0, ss); ss = fmaf(f1, f1, ss);
        ss = fmaf(f2, f2, ss); ss = fmaf(f3, f3, ss);

        const float4 v0 = *reinterpret_cast<const float4*>(fn + 0 * DFULL + j);
        const float4 v1 = *reinterpret_cast<const float4*>(fn + 1 * DFULL + j);
        const float4 v2 = *reinterpret_cast<const float4*>(fn + 2 * DFULL + j);
        const float4 v3 = *reinterpret_cast<const float4*>(fn + 3 * DFULL + j);

        d0 = fmaf(f0, v0.x, d0); d0 = fmaf(f1, v0.y, d0);
        d0 = fmaf(f2, v0.z, d0); d0 = fmaf(f3, v0.w, d0);
        d1 = fmaf(f0, v1.x, d1); d1 = fmaf(f1, v1.y, d1);
        d1 = fmaf(f2, v1.z, d1); d1 = fmaf(f3, v1.w, d1);
        d2 = fmaf(f0, v2.x, d2); d2 = fmaf(f1, v2.y, d2);
        d2 = fmaf(f2, v2.z, d2); d2 = fmaf(f3, v2.w, d2);
        d3 = fmaf(f0, v3.x, d3); d3 = fmaf(f1, v3.y, d3);
        d3 = fmaf(f2, v3.z, d3); d3 = fmaf(f3, v3.w, d3);
    }

    // Wave-level butterfly reduction (64 lanes), then cross-wave via LDS.
    float v[5] = {ss, d0, d1, d2, d3};
    #pragma unroll
    for (int k = 0; k < 5; ++k) {
        float s = v[k];
        #pragma unroll
        for (int off = 32; off > 0; off >>= 1)
            s += __shfl_xor(s, off, 64);
        v[k] = s;
    }
    const int wave = tid >> 6;
    if ((tid & 63) == 0) {
        #pragma unroll
        for (int k = 0; k < 5; ++k) red[wave][k] = v[k];
    }
    __syncthreads();

    if (tid == 0) {
        float sums[5];
        #pragma unroll
        for (int k = 0; k < 5; ++k)
            sums[k] = red[0][k] + red[1][k] + red[2][k] + red[3][k];
        const float rms  = sqrtf(sums[0] * (1.f / DFULL) + 1e-6f);
        const float inv  = 1.f / rms;
        const float sc   = scale[0];
        float a0 = fmaf(sc, sums[1] * inv, base[0]);
        float a1 = fmaf(sc, sums[2] * inv, base[1]);
        float a2 = fmaf(sc, sums[3] * inv, base[2]);
        float a3 = fmaf(sc, sums[4] * inv, base[3]);
        const float den = fabsf(a0) + fabsf(a1) + fabsf(a2) + fabsf(a3) + 1e-6f;
        const float idn = 1.f / den;
        wbc[0] = a0 * idn; wbc[1] = a1 * idn;
        wbc[2] = a2 * idn; wbc[3] = a3 * idn;
    }
    __syncthreads();

    const float w0 = wbc[0], w1 = wbc[1], w2 = wbc[2], w3 = wbc[3];
    float* orow = out + (size_t)t * HIDDEN;

    // Phase 2: weighted combine of the 4 streams from LDS, coalesced float4 out.
    #pragma unroll
    for (int it = 0; it < HIDDEN / (NTHREADS * 4); ++it) {
        const int h = (it * NTHREADS + tid) * 4;
        const ushort4 u0 = *reinterpret_cast<const ushort4*>(&xb[0 * HIDDEN + h]);
        const ushort4 u1 = *reinterpret_cast<const ushort4*>(&xb[1 * HIDDEN + h]);
        const ushort4 u2 = *reinterpret_cast<const ushort4*>(&xb[2 * HIDDEN + h]);
        const ushort4 u3 = *reinterpret_cast<const ushort4*>(&xb[3 * HIDDEN + h]);
        float4 o;
        o.x = w0 * b2f(u0.x) + w1 * b2f(u1.x) + w2 * b2f(u2.x) + w3 * b2f(u3.x);
        o.y = w0 * b2f(u0.y) + w1 * b2f(u1.y) + w2 * b2f(u2.y) + w3 * b2f(u3.y);
        o.z = w0 * b2f(u0.z) + w1 * b2f(u1.z) + w2 * b2f(u2.z) + w3 * b2f(u3.z);
        o.w = w0 * b2f(u0.w) + w1 * b2f(u1.w) + w2 * b2f(u2.w) + w3 * b2f(u3.w);
        *reinterpret_cast<float4*>(orow + h) = o;
    }
}

extern "C" void kernel_launch(void* const* d_in, const int* in_sizes, int n_in,
                              void* d_out, int out_size, void* d_ws, size_t ws_size,
                              hipStream_t stream) {
    const float* x     = (const float*)d_in[0];
    const float* fn    = (const float*)d_in[1];
    const float* scale = (const float*)d_in[2];
    const float* base  = (const float*)d_in[3];
    float* out = (float*)d_out;
    const int T = in_sizes[0] / DFULL;
    hchead_kernel<<<T, NTHREADS, 0, stream>>>(x, fn, scale, base, out);
}